// Round 5
// baseline (157.258 us; speedup 1.0000x reference)
//
#include <hip/hip_runtime.h>

#define OUT_MU 131072
#define OUT_OM 262144
#define BIAS_OFF 4194304              // half-index of bias pack inside d_ws
#define WOUT_OFF 4210688              // half-index of packed W_out

typedef _Float16 half8 __attribute__((ext_vector_type(8)));
typedef _Float16 half4 __attribute__((ext_vector_type(4)));
typedef float    floatx4 __attribute__((ext_vector_type(4)));

__device__ __forceinline__ void wait_lgkm0() {
    asm volatile("s_waitcnt lgkmcnt(0)" ::: "memory");
}
__device__ __forceinline__ void barrier_raw() {
    asm volatile("s_barrier" ::: "memory");
}

// ---------------------------------------------------------------------------
// Repack hidden weights fp32 -> fp16 as
//   [ch(16)][g(32)][wv(4)][nt(4)][ks(4)][r16(16)][e(8)]   (half8 units)
// Lane l of wave wv loads its exact MFMA A-fragment for (g, nt) with one
// global_load_dwordx4. Strides (half8): ch=32768, g=1024, wv=256, nt=64,
// lane = ks*16+r16.
// A-frag (16x16x32_f16): lane l holds row n = nt*16 + (l&15),
//                        k = (g&7)*32 + (l>>4)*8 + e.
// ---------------------------------------------------------------------------
__global__ void prep_w(const float* __restrict__ Wr_h,
                       const float* __restrict__ Wc_h,
                       _Float16* __restrict__ dst) {
    int v = blockIdx.x * 256 + threadIdx.x;        // 524288 half8 slots
    int r16 = v & 15;
    int ks  = (v >> 4) & 3;
    int nt  = (v >> 6) & 3;
    int wv  = (v >> 8) & 3;
    int g   = (v >> 10) & 31;
    int ch  = v >> 15;
    int l = g >> 3, kk = g & 7;
    int n  = wv * 64 + nt * 16 + r16;
    int k0 = kk * 32 + ks * 8;
    const float* src = (ch < 8) ? Wr_h : Wc_h;
    int c = ch & 7;
    const float* p = src + ((size_t)((l * 8 + c) * 256 + n)) * 256 + k0;
    float4 a = *(const float4*)p;
    float4 b = *(const float4*)(p + 4);
    half8 o;
    o[0] = (_Float16)a.x; o[1] = (_Float16)a.y; o[2] = (_Float16)a.z; o[3] = (_Float16)a.w;
    o[4] = (_Float16)b.x; o[5] = (_Float16)b.y; o[6] = (_Float16)b.z; o[7] = (_Float16)b.w;
    *(half8*)(dst + (size_t)v * 8) = o;
}

// Bias pack: per (ch, wv, rq): 64 halves [l(4)][nthi(2)] half8s of [ntlo(2)][e(4)].
__global__ void prep_b(const float* __restrict__ br_h,
                       const float* __restrict__ bc_h,
                       _Float16* __restrict__ dst) {
    int t = blockIdx.x * 256 + threadIdx.x;        // 16384
    int idx = t & 63, blk = t >> 6;
    int rq = blk & 3, wv = (blk >> 2) & 3, ch = blk >> 4;
    int j = idx >> 3, rem = idx & 7;
    int l = j >> 1, nthi = j & 1;
    int ntlo = rem >> 2, e = rem & 3;
    int nt = nthi * 2 + ntlo;
    int n = wv * 64 + nt * 16 + rq * 4 + e;
    const float* src = (ch < 8) ? br_h : bc_h;
    dst[BIAS_OFF + t] = (_Float16)src[(l * 8 + (ch & 7)) * 256 + n];
}

// W_out pack: [ch(16)][d(2)][j(256)] fp16 (real channels use d=0 only).
__global__ void prep_wo(const float* __restrict__ Wr_out,
                        const float* __restrict__ Wc_out,
                        _Float16* __restrict__ dst) {
    int t = blockIdx.x * 256 + threadIdx.x;        // 8192
    int j = t & 255, d = (t >> 8) & 1, ch = t >> 9;
    int c = ch & 7;
    float v;
    if (ch < 8) v = d ? 0.f : Wr_out[c * 256 + j];
    else        v = Wc_out[(c * 2 + d) * 256 + j];
    dst[WOUT_OFF + t] = (_Float16)v;
}

// ---------------------------------------------------------------------------
// Fused MLP. Block = (ch = bid&15, 64 rows). h (64x256 fp16, swizzled, 32 KB)
// lives in LDS across all layers; weights go global->VGPR (wave-exact
// fragments, register double-buffer, depth-1). K-loop has NO barriers;
// 2 per layer edge. Wave wv owns n in [wv*64, wv*64+64), all 64 m rows.
// ---------------------------------------------------------------------------
__global__ __launch_bounds__(256, 3)
void mlp_fused(const float* __restrict__ z,
               const float* __restrict__ Wr_in, const float* __restrict__ br_in,
               const float* __restrict__ Wc_in, const float* __restrict__ bc_in,
               const float* __restrict__ br_out, const float* __restrict__ bc_out,
               const _Float16* __restrict__ wst,
               float* __restrict__ out) {
    __shared__ __align__(16) char smem[32768];     // h: 64 rows x 512 B
    const int tid  = threadIdx.x;
    const int lane = tid & 63;
    const int wv   = tid >> 6;
    const int bid  = blockIdx.x;
    const int ch   = bid & 15;                     // all same-ch blocks on one XCD
    const int m0   = (bid >> 4) * 64;
    const bool isC = ch >= 8;
    const int c    = ch & 7;
    const int ks   = lane >> 4;
    const int r16  = lane & 15;

    // weight fragments: wlane[g*1024 + nt*64] is this lane's half8 for (g, nt)
    const half8* wlane = (const half8*)wst + (size_t)ch * 32768 + wv * 256 + lane;
    const half8* bp = (const half8*)(wst + BIAS_OFF) + (((ch * 4 + wv) * 4 + ks) * 8);

    half8 wa[4], wb[4];
    #pragma unroll
    for (int nt = 0; nt < 4; ++nt) wa[nt] = wlane[nt * 64];   // g = 0 (issued early)

    // bf base addresses: addr(mt, kk) = vb[mt] ^ (kk<<6)
    // vb = m*512 + (((r16&7)^ks)<<4), m = mt*16+r16; kk<<6 bits are disjoint-safe.
    int vb[4];
    #pragma unroll
    for (int mt = 0; mt < 4; ++mt)
        vb[mt] = (mt * 16 + r16) * 512 + (((r16 & 7) ^ ks) << 4);

    // ---- input layer: h0[m][j] = relu(x_m * W_in[j] + b_in[j]) ----
    {
        const int jg = tid & 31;                   // j0 = jg*8
        const int rg = tid >> 5;                   // rows rg*8 .. rg*8+7
        const float* Wi = (isC ? Wc_in : Wr_in) + c * 256 + jg * 8;
        const float* bi = (isC ? bc_in : br_in) + c * 256 + jg * 8;
        float4 w0 = *(const float4*)Wi;
        float4 w1 = *(const float4*)(Wi + 4);
        float4 v0 = *(const float4*)bi;
        float4 v1 = *(const float4*)(bi + 4);
        #pragma unroll
        for (int i = 0; i < 8; ++i) {
            int m = rg * 8 + i;
            const float* zr = z + (size_t)(m0 + m) * 24;
            float x;
            if (!isC) x = zr[c];
            else { float a = zr[8 + 2 * c], b = zr[9 + 2 * c]; x = a * a + b * b; }
            half8 o;
            o[0] = (_Float16)fmaxf(fmaf(x, w0.x, v0.x), 0.f);
            o[1] = (_Float16)fmaxf(fmaf(x, w0.y, v0.y), 0.f);
            o[2] = (_Float16)fmaxf(fmaf(x, w0.z, v0.z), 0.f);
            o[3] = (_Float16)fmaxf(fmaf(x, w0.w, v0.w), 0.f);
            o[4] = (_Float16)fmaxf(fmaf(x, w1.x, v1.x), 0.f);
            o[5] = (_Float16)fmaxf(fmaf(x, w1.y, v1.y), 0.f);
            o[6] = (_Float16)fmaxf(fmaf(x, w1.z, v1.z), 0.f);
            o[7] = (_Float16)fmaxf(fmaf(x, w1.w, v1.w), 0.f);
            *(half8*)(smem + m * 512 + ((jg ^ (m & 7)) << 4)) = o;
        }
    }
    wait_lgkm0();
    barrier_raw();                                  // h0 visible

#define STEP(KK, WREG) do {                                                       \
        half8 bf[4];                                                              \
        _Pragma("unroll")                                                         \
        for (int mt = 0; mt < 4; ++mt)                                            \
            bf[mt] = *(const half8*)(smem + (vb[mt] ^ ((KK) << 6)));              \
        __builtin_amdgcn_s_setprio(1);                                            \
        _Pragma("unroll")                                                         \
        for (int nt = 0; nt < 4; ++nt)                                            \
            _Pragma("unroll")                                                     \
            for (int mt = 0; mt < 4; ++mt)                                        \
                acc[nt][mt] = __builtin_amdgcn_mfma_f32_16x16x32_f16(             \
                    WREG[nt], bf[mt], acc[nt][mt], 0, 0, 0);                      \
        __builtin_amdgcn_s_setprio(0);                                            \
    } while (0)

    #pragma unroll 1
    for (int l = 0; l < 4; ++l) {
        floatx4 acc[4][4];
        #pragma unroll
        for (int a = 0; a < 4; ++a)
            #pragma unroll
            for (int b = 0; b < 4; ++b) acc[a][b] = 0.f;

        #pragma unroll
        for (int kk = 0; kk < 8; kk += 2) {
            {   // even step: consume wa, prefetch g = l*8+kk+1 into wb
                const half8* p = wlane + (size_t)(l * 8 + kk + 1) * 1024;
                #pragma unroll
                for (int nt = 0; nt < 4; ++nt) wb[nt] = p[nt * 64];
                STEP(kk, wa);
            }
            {   // odd step: consume wb, prefetch g = l*8+kk+2 into wa
                int g1 = l * 8 + kk + 2;
                if (g1 < 32) {
                    const half8* p = wlane + (size_t)g1 * 1024;
                    #pragma unroll
                    for (int nt = 0; nt < 4; ++nt) wa[nt] = p[nt * 64];
                }
                STEP(kk + 1, wb);
            }
        }

        // bias for this layer (transient registers, loaded under the barrier)
        half8 bl0 = bp[l * 2], bl1 = bp[l * 2 + 1];

        // ---- layer epilogue: bias + relu -> h (in place) ----
        wait_lgkm0();
        barrier_raw();                              // all reads of layer l done
        #pragma unroll
        for (int nt = 0; nt < 4; ++nt) {
            const int nb = wv * 64 + nt * 16 + ks * 4;
            half8 bv = (nt < 2) ? bl0 : bl1;
            float b0 = (float)bv[(nt & 1) * 4 + 0];
            float b1 = (float)bv[(nt & 1) * 4 + 1];
            float b2 = (float)bv[(nt & 1) * 4 + 2];
            float b3 = (float)bv[(nt & 1) * 4 + 3];
            #pragma unroll
            for (int mt = 0; mt < 4; ++mt) {
                const int m = mt * 16 + r16;
                floatx4 v = acc[nt][mt];
                half4 o;
                o[0] = (_Float16)fmaxf(v[0] + b0, 0.f);
                o[1] = (_Float16)fmaxf(v[1] + b1, 0.f);
                o[2] = (_Float16)fmaxf(v[2] + b2, 0.f);
                o[3] = (_Float16)fmaxf(v[3] + b3, 0.f);
                *(half4*)(smem + m * 512 + (((nb >> 3) ^ (m & 7)) << 4) + (nb & 7) * 2) = o;
            }
        }
        wait_lgkm0();
        barrier_raw();                              // new h visible
    }
#undef STEP

    // ---- output layer: 4 threads/row, fp16 packed W_out ----
    {
        const int q = tid & 3, m = tid >> 2;       // m in 0..63
        const half8* Wo = (const half8*)(wst + WOUT_OFF) + ch * 64;
        float s0 = 0.f, s1 = 0.f;
        #pragma unroll
        for (int i = 0; i < 8; ++i) {
            int slot = q * 8 + i;
            half8 hv = *(const half8*)(smem + m * 512 + ((slot ^ (m & 7)) << 4));
            half8 w0 = Wo[slot];
            #pragma unroll
            for (int e = 0; e < 8; ++e) s0 = fmaf((float)hv[e], (float)w0[e], s0);
            if (isC) {
                half8 w1 = Wo[32 + slot];
                #pragma unroll
                for (int e = 0; e < 8; ++e) s1 = fmaf((float)hv[e], (float)w1[e], s1);
            }
        }
        s0 += __shfl_xor(s0, 1); s0 += __shfl_xor(s0, 2);
        if (isC) { s1 += __shfl_xor(s1, 1); s1 += __shfl_xor(s1, 2); }
        if (q == 0) {
            const int row = m0 + m;
            if (!isC) {
                out[row * 8 + c] = s0 + br_out[c];
            } else {
                out[OUT_MU + row * 8 + c] = s0 + bc_out[c * 2];
                out[OUT_OM + row * 8 + c] = s1 + bc_out[c * 2 + 1];
            }
        }
    }
}

extern "C" void kernel_launch(void* const* d_in, const int* in_sizes, int n_in,
                              void* d_out, int out_size, void* d_ws, size_t ws_size,
                              hipStream_t stream) {
    const float* z      = (const float*)d_in[0];
    const float* Wr_in  = (const float*)d_in[1];
    const float* br_in  = (const float*)d_in[2];
    const float* Wr_h   = (const float*)d_in[3];
    const float* br_h   = (const float*)d_in[4];
    const float* Wr_out = (const float*)d_in[5];
    const float* br_out = (const float*)d_in[6];
    const float* Wc_in  = (const float*)d_in[7];
    const float* bc_in  = (const float*)d_in[8];
    const float* Wc_h   = (const float*)d_in[9];
    const float* bc_h   = (const float*)d_in[10];
    const float* Wc_out = (const float*)d_in[11];
    const float* bc_out = (const float*)d_in[12];
    _Float16* wst = (_Float16*)d_ws;               // 8 MB weights + bias + wout packs
    float* out = (float*)d_out;

    prep_w<<<2048, 256, 0, stream>>>(Wr_h, Wc_h, wst);
    prep_b<<<64, 256, 0, stream>>>(br_h, bc_h, wst);
    prep_wo<<<32, 256, 0, stream>>>(Wr_out, Wc_out, wst);
    mlp_fused<<<4096, 256, 0, stream>>>(z, Wr_in, br_in, Wc_in, bc_in,
                                        br_out, bc_out, wst, out);
}

// Round 6
// 138.225 us; speedup vs baseline: 1.1377x; 1.1377x over previous
//
#include <hip/hip_runtime.h>

#define OUT_MU 131072
#define OUT_OM 262144
#define BIAS_OFF 4194304              // half-index of bias pack inside d_ws
#define WOUT_OFF 4210688              // half-index of packed W_out

typedef _Float16 half8 __attribute__((ext_vector_type(8)));
typedef _Float16 half4 __attribute__((ext_vector_type(4)));
typedef float    floatx4 __attribute__((ext_vector_type(4)));

__device__ __forceinline__ void wait_lgkm0() {
    asm volatile("s_waitcnt lgkmcnt(0)" ::: "memory");
}
__device__ __forceinline__ void barrier_raw() {
    asm volatile("s_barrier" ::: "memory");
}

// ---------------------------------------------------------------------------
// Repack hidden weights fp32 -> fp16 as
//   [ch(16)][g(32)][wv(4)][nt(4)][ks(4)][r16(16)][e(8)]   (half8 units)
// Lane l of wave wv loads its exact MFMA A-fragment for (g, nt) with one
// global_load_dwordx4. Strides (half8): ch=32768, g=1024, wv=256, nt=64,
// lane = ks*16+r16.
// A-frag (16x16x32_f16): lane l holds row n = nt*16 + (l&15),
//                        k = (g&7)*32 + (l>>4)*8 + e.
// ---------------------------------------------------------------------------
__global__ void prep_w(const float* __restrict__ Wr_h,
                       const float* __restrict__ Wc_h,
                       _Float16* __restrict__ dst) {
    int v = blockIdx.x * 256 + threadIdx.x;        // 524288 half8 slots
    int r16 = v & 15;
    int ks  = (v >> 4) & 3;
    int nt  = (v >> 6) & 3;
    int wv  = (v >> 8) & 3;
    int g   = (v >> 10) & 31;
    int ch  = v >> 15;
    int l = g >> 3, kk = g & 7;
    int n  = wv * 64 + nt * 16 + r16;
    int k0 = kk * 32 + ks * 8;
    const float* src = (ch < 8) ? Wr_h : Wc_h;
    int c = ch & 7;
    const float* p = src + ((size_t)((l * 8 + c) * 256 + n)) * 256 + k0;
    float4 a = *(const float4*)p;
    float4 b = *(const float4*)(p + 4);
    half8 o;
    o[0] = (_Float16)a.x; o[1] = (_Float16)a.y; o[2] = (_Float16)a.z; o[3] = (_Float16)a.w;
    o[4] = (_Float16)b.x; o[5] = (_Float16)b.y; o[6] = (_Float16)b.z; o[7] = (_Float16)b.w;
    *(half8*)(dst + (size_t)v * 8) = o;
}

// Bias pack: per (ch, wv, rq): 64 halves [l(4)][nthi(2)] half8s of [ntlo(2)][e(4)].
__global__ void prep_b(const float* __restrict__ br_h,
                       const float* __restrict__ bc_h,
                       _Float16* __restrict__ dst) {
    int t = blockIdx.x * 256 + threadIdx.x;        // 16384
    int idx = t & 63, blk = t >> 6;
    int rq = blk & 3, wv = (blk >> 2) & 3, ch = blk >> 4;
    int j = idx >> 3, rem = idx & 7;
    int l = j >> 1, nthi = j & 1;
    int ntlo = rem >> 2, e = rem & 3;
    int nt = nthi * 2 + ntlo;
    int n = wv * 64 + nt * 16 + rq * 4 + e;
    const float* src = (ch < 8) ? br_h : bc_h;
    dst[BIAS_OFF + t] = (_Float16)src[(l * 8 + (ch & 7)) * 256 + n];
}

// W_out pack: [ch(16)][d(2)][j(256)] fp16 (real channels use d=0 only).
__global__ void prep_wo(const float* __restrict__ Wr_out,
                        const float* __restrict__ Wc_out,
                        _Float16* __restrict__ dst) {
    int t = blockIdx.x * 256 + threadIdx.x;        // 8192
    int j = t & 255, d = (t >> 8) & 1, ch = t >> 9;
    int c = ch & 7;
    float v;
    if (ch < 8) v = d ? 0.f : Wr_out[c * 256 + j];
    else        v = Wc_out[(c * 2 + d) * 256 + j];
    dst[WOUT_OFF + t] = (_Float16)v;
}

// ---------------------------------------------------------------------------
// Fused MLP. Block = (ch = bid&15, 128 rows). h (128x256 fp16, swizzled,
// 64 KB) lives in LDS across all layers. Weights: global->VGPR wave-exact
// fragments, register double-buffer (depth ~2 half-steps). Activations:
// register double-buffer at 4-fragment half-step granularity, so ds_read
// latency hides under the previous half-step's 16 MFMAs. K-loop: NO barriers.
// Wave wv owns n in [wv*64, wv*64+64), all 128 m rows: acc[4][8].
// ---------------------------------------------------------------------------
__global__ __launch_bounds__(256, 2)
void mlp_fused(const float* __restrict__ z,
               const float* __restrict__ Wr_in, const float* __restrict__ br_in,
               const float* __restrict__ Wc_in, const float* __restrict__ bc_in,
               const float* __restrict__ br_out, const float* __restrict__ bc_out,
               const _Float16* __restrict__ wst,
               float* __restrict__ out) {
    __shared__ __align__(16) char smem[65536];     // h: 128 rows x 512 B
    const int tid  = threadIdx.x;
    const int lane = tid & 63;
    const int wv   = tid >> 6;
    const int bid  = blockIdx.x;
    const int ch   = bid & 15;                     // all same-ch blocks on one XCD
    const int m0   = (bid >> 4) * 128;
    const bool isC = ch >= 8;
    const int c    = ch & 7;
    const int ks   = lane >> 4;
    const int r16  = lane & 15;

    // weight fragments: wl[g*1024 + nt*64] is this lane's half8 for (g, nt)
    const half8* wl = (const half8*)wst + (size_t)ch * 32768 + wv * 256 + lane;
    const half8* bp = (const half8*)(wst + BIAS_OFF) + (((ch * 4 + wv) * 4 + ks) * 8);

    half8 wr[2][4];
    #pragma unroll
    for (int nt = 0; nt < 4; ++nt) wr[0][nt] = wl[nt * 64];   // g = 0, issued early

    // bf base addresses: addr(mt, kk) = vb[mt] ^ (kk<<6)   (verified R5)
    int vb[8];
    #pragma unroll
    for (int mt = 0; mt < 8; ++mt)
        vb[mt] = (mt * 16 + r16) * 512 + (((r16 & 7) ^ ks) << 4);

    // ---- input layer: h0[m][j] = relu(x_m * W_in[j] + b_in[j]) ----
    {
        const int jg = tid & 31;                   // j0 = jg*8
        const int rg = tid >> 5;                   // rows rg*16 .. rg*16+15
        const float* Wi = (isC ? Wc_in : Wr_in) + c * 256 + jg * 8;
        const float* bi = (isC ? bc_in : br_in) + c * 256 + jg * 8;
        float4 w0 = *(const float4*)Wi;
        float4 w1 = *(const float4*)(Wi + 4);
        float4 v0 = *(const float4*)bi;
        float4 v1 = *(const float4*)(bi + 4);
        #pragma unroll
        for (int i = 0; i < 16; ++i) {
            int m = rg * 16 + i;
            const float* zr = z + (size_t)(m0 + m) * 24;
            float x;
            if (!isC) x = zr[c];
            else { float a = zr[8 + 2 * c], b = zr[9 + 2 * c]; x = a * a + b * b; }
            half8 o;
            o[0] = (_Float16)fmaxf(fmaf(x, w0.x, v0.x), 0.f);
            o[1] = (_Float16)fmaxf(fmaf(x, w0.y, v0.y), 0.f);
            o[2] = (_Float16)fmaxf(fmaf(x, w0.z, v0.z), 0.f);
            o[3] = (_Float16)fmaxf(fmaf(x, w0.w, v0.w), 0.f);
            o[4] = (_Float16)fmaxf(fmaf(x, w1.x, v1.x), 0.f);
            o[5] = (_Float16)fmaxf(fmaf(x, w1.y, v1.y), 0.f);
            o[6] = (_Float16)fmaxf(fmaf(x, w1.z, v1.z), 0.f);
            o[7] = (_Float16)fmaxf(fmaf(x, w1.w, v1.w), 0.f);
            *(half8*)(smem + m * 512 + ((jg ^ (m & 7)) << 4)) = o;
        }
    }
    wait_lgkm0();
    barrier_raw();                                  // h0 visible

    #pragma unroll 1
    for (int l = 0; l < 4; ++l) {
        // bias for this layer (transient, latency hidden under K-loop)
        half8 bl0 = bp[l * 2], bl1 = bp[l * 2 + 1];

        floatx4 acc[4][8];
        #pragma unroll
        for (int a = 0; a < 4; ++a)
            #pragma unroll
            for (int b = 0; b < 8; ++b) acc[a][b] = 0.f;

        half8 bfr[2][4];
        // layer prologue: activation fragments for (kk=0, half=0)
        #pragma unroll
        for (int j = 0; j < 4; ++j)
            bfr[0][j] = *(const half8*)(smem + vb[j]);

        #pragma unroll
        for (int hs = 0; hs < 16; ++hs) {
            const int kk = hs >> 1, half = hs & 1;
            // weight prefetch: once per kk, for kk+1 (crosses layer edge;
            // final g=32 read lands in the bias-pack region — harmless)
            if (half == 0) {
                const half8* p = wl + (kk + 1) * 1024;
                #pragma unroll
                for (int nt = 0; nt < 4; ++nt) wr[(kk + 1) & 1][nt] = p[nt * 64];
            }
            // activation prefetch for next half-step
            if (hs < 15) {
                const int nkk = (hs + 1) >> 1, nhalf = (hs + 1) & 1;
                #pragma unroll
                for (int j = 0; j < 4; ++j)
                    bfr[nhalf][j] = *(const half8*)(smem + (vb[nhalf * 4 + j] ^ (nkk << 6)));
            }
            __builtin_amdgcn_s_setprio(1);
            #pragma unroll
            for (int nt = 0; nt < 4; ++nt)
                #pragma unroll
                for (int j = 0; j < 4; ++j)
                    acc[nt][half * 4 + j] = __builtin_amdgcn_mfma_f32_16x16x32_f16(
                        wr[kk & 1][nt], bfr[half][j], acc[nt][half * 4 + j], 0, 0, 0);
            __builtin_amdgcn_s_setprio(0);
        }
        wl += 8192;                                 // next layer's weights

        // ---- layer epilogue: bias + relu -> h (in place) ----
        wait_lgkm0();
        barrier_raw();                              // all reads of layer l done
        #pragma unroll
        for (int nt = 0; nt < 4; ++nt) {
            const int nb = wv * 64 + nt * 16 + ks * 4;
            half8 bv = (nt < 2) ? bl0 : bl1;
            float b0 = (float)bv[(nt & 1) * 4 + 0];
            float b1 = (float)bv[(nt & 1) * 4 + 1];
            float b2 = (float)bv[(nt & 1) * 4 + 2];
            float b3 = (float)bv[(nt & 1) * 4 + 3];
            #pragma unroll
            for (int mt = 0; mt < 8; ++mt) {
                const int m = mt * 16 + r16;
                floatx4 v = acc[nt][mt];
                half4 o;
                o[0] = (_Float16)fmaxf(v[0] + b0, 0.f);
                o[1] = (_Float16)fmaxf(v[1] + b1, 0.f);
                o[2] = (_Float16)fmaxf(v[2] + b2, 0.f);
                o[3] = (_Float16)fmaxf(v[3] + b3, 0.f);
                *(half4*)(smem + m * 512 + (((nb >> 3) ^ (m & 7)) << 4) + (nb & 7) * 2) = o;
            }
        }
        wait_lgkm0();
        barrier_raw();                              // new h visible
    }

    // ---- output layer: 2 threads/row, fp16 packed W_out ----
    {
        const int q = tid & 1, m = tid >> 1;       // m in 0..127
        const half8* Wo = (const half8*)(wst + WOUT_OFF) + ch * 64 + q * 16;
        float s0 = 0.f, s1 = 0.f;
        #pragma unroll
        for (int i = 0; i < 16; ++i) {
            int slot = q * 16 + i;
            half8 hv = *(const half8*)(smem + m * 512 + ((slot ^ (m & 7)) << 4));
            half8 w0 = Wo[i];
            #pragma unroll
            for (int e = 0; e < 8; ++e) s0 = fmaf((float)hv[e], (float)w0[e], s0);
            if (isC) {
                half8 w1 = Wo[32 + i];
                #pragma unroll
                for (int e = 0; e < 8; ++e) s1 = fmaf((float)hv[e], (float)w1[e], s1);
            }
        }
        s0 += __shfl_xor(s0, 1);
        if (isC) s1 += __shfl_xor(s1, 1);
        if (q == 0) {
            const int row = m0 + m;
            if (!isC) {
                out[row * 8 + c] = s0 + br_out[c];
            } else {
                out[OUT_MU + row * 8 + c] = s0 + bc_out[c * 2];
                out[OUT_OM + row * 8 + c] = s1 + bc_out[c * 2 + 1];
            }
        }
    }
}

extern "C" void kernel_launch(void* const* d_in, const int* in_sizes, int n_in,
                              void* d_out, int out_size, void* d_ws, size_t ws_size,
                              hipStream_t stream) {
    const float* z      = (const float*)d_in[0];
    const float* Wr_in  = (const float*)d_in[1];
    const float* br_in  = (const float*)d_in[2];
    const float* Wr_h   = (const float*)d_in[3];
    const float* br_h   = (const float*)d_in[4];
    const float* Wr_out = (const float*)d_in[5];
    const float* br_out = (const float*)d_in[6];
    const float* Wc_in  = (const float*)d_in[7];
    const float* bc_in  = (const float*)d_in[8];
    const float* Wc_h   = (const float*)d_in[9];
    const float* bc_h   = (const float*)d_in[10];
    const float* Wc_out = (const float*)d_in[11];
    const float* bc_out = (const float*)d_in[12];
    _Float16* wst = (_Float16*)d_ws;               // 8 MB weights + bias + wout packs
    float* out = (float*)d_out;

    prep_w<<<2048, 256, 0, stream>>>(Wr_h, Wc_h, wst);
    prep_b<<<64, 256, 0, stream>>>(br_h, bc_h, wst);
    prep_wo<<<32, 256, 0, stream>>>(Wr_out, Wc_out, wst);
    mlp_fused<<<2048, 256, 0, stream>>>(z, Wr_in, br_in, Wc_in, bc_in,
                                        br_out, bc_out, wst, out);
}